// Round 4
// baseline (226.479 us; speedup 1.0000x reference)
//
#include <hip/hip_runtime.h>
#include <hip/hip_bf16.h>
#include <stdint.h>

#define BB 2
#define SS 2048
#define HH 1024
#define NHH 16
#define HDD 64
#define MM (BB*SS)      // 4096
#define N1 (3*HH)       // 3072
#define NT (SS/64)      // 32 kv tiles
#define LOG2E 1.44269504f

using bf16 = __hip_bfloat16;
typedef __attribute__((ext_vector_type(8))) short bf16x8;
typedef __attribute__((ext_vector_type(4))) float f32x4;
typedef __attribute__((ext_vector_type(16))) float f32x16;

__device__ inline unsigned short f2bfu(float f) {
  union { bf16 h; unsigned short u; } c;
  c.h = __float2bfloat16(f);
  return c.u;
}

__device__ inline unsigned int packbf(float lo, float hi) {
  return (unsigned int)f2bfu(lo) | ((unsigned int)f2bfu(hi) << 16);
}

__device__ inline void load_lds16(const void* g, void* l) {
  __builtin_amdgcn_global_load_lds(
      (const __attribute__((address_space(1))) void*)g,
      (__attribute__((address_space(3))) void*)l, 16, 0, 0);
}

__device__ inline f32x4 mfma16(bf16x8 a, bf16x8 b, f32x4 c) {
  return __builtin_amdgcn_mfma_f32_16x16x32_bf16(a, b, c, 0, 0, 0);
}
__device__ inline f32x16 mfma32(bf16x8 a, bf16x8 b, f32x16 c) {
  return __builtin_amdgcn_mfma_f32_32x32x16_bf16(a, b, c, 0, 0, 0);
}

// ---------------- fp32 -> bf16 convert ----------------
__global__ __launch_bounds__(256) void cvt_f32_bf16(const float* __restrict__ in,
                                                    unsigned short* __restrict__ out,
                                                    int n4) {
  int i = blockIdx.x * blockDim.x + threadIdx.x;
  int st = gridDim.x * blockDim.x;
  for (; i < n4; i += st) {
    float4 v = reinterpret_cast<const float4*>(in)[i];
    ushort4 o;
    o.x = f2bfu(v.x); o.y = f2bfu(v.y); o.z = f2bfu(v.z); o.w = f2bfu(v.w);
    reinterpret_cast<ushort4*>(out)[i] = o;
  }
}

// ---------------- mask tile flags: 1 if 64x64 tile is all ones ----------------
__global__ __launch_bounds__(256) void mask_flags_kernel(const float* __restrict__ mask,
                                                         unsigned char* __restrict__ flags) {
  int t = blockIdx.x;
  int b = t >> 10, qt = (t >> 5) & 31, kt = t & 31;
  const float* mb = mask + ((size_t)b * SS + qt * 64) * SS + kt * 64;
  int row = threadIdx.x >> 2, c0 = (threadIdx.x & 3) * 16;
  int ok = 1;
#pragma unroll
  for (int j = 0; j < 4; ++j) {
    float4 v = *reinterpret_cast<const float4*>(mb + (size_t)row * SS + c0 + j * 4);
    ok &= (v.x == 1.f) & (v.y == 1.f) & (v.z == 1.f) & (v.w == 1.f);
  }
  ok = __all(ok);
  __shared__ int s[4];
  if ((threadIdx.x & 63) == 0) s[threadIdx.x >> 6] = ok;
  __syncthreads();
  if (threadIdx.x == 0) flags[t] = (unsigned char)(s[0] & s[1] & s[2] & s[3]);
}

// ---------------- GEMM: C[m][n] = sum_k A[m][k]*Bt[n][k] + bias[n] ----------------
template <bool OUT_BF16>
__global__ __launch_bounds__(256) void gemm_bt(const unsigned short* __restrict__ A,
                                               const unsigned short* __restrict__ Bt,
                                               const float* __restrict__ bias,
                                               void* __restrict__ Cv,
                                               int Ndim, int Kdim) {
  __shared__ __align__(16) unsigned short As[128 * 32];
  __shared__ __align__(16) unsigned short Bs[128 * 32];

  const int tid = threadIdx.x;
  const int wave = tid >> 6, lane = tid & 63;
  const int m0 = blockIdx.x * 128;
  const int n0 = blockIdx.y * 128;
  const int wm = (wave >> 1) * 64, wn = (wave & 1) * 64;
  const int lrow = lane & 15;
  const int lk8 = (lane >> 4) * 8;
  const int r4 = (lane >> 4) * 4;

  f32x4 acc[4][4];
  const f32x4 z = {0.f, 0.f, 0.f, 0.f};
  for (int i = 0; i < 4; ++i)
    for (int j = 0; j < 4; ++j) acc[i][j] = z;

  for (int k0 = 0; k0 < Kdim; k0 += 32) {
#pragma unroll
    for (int it = 0; it < 2; ++it) {
      int idx = it * 256 + tid;
      int row = idx >> 2, seg = idx & 3;
      load_lds16(A + (size_t)(m0 + row) * Kdim + k0 + seg * 8, &As[row * 32 + seg * 8]);
      load_lds16(Bt + (size_t)(n0 + row) * Kdim + k0 + seg * 8, &Bs[row * 32 + seg * 8]);
    }
    __syncthreads();

    bf16x8 af[4], bfr[4];
#pragma unroll
    for (int i = 0; i < 4; ++i)
      af[i] = *reinterpret_cast<const bf16x8*>(&As[(wm + i * 16 + lrow) * 32 + lk8]);
#pragma unroll
    for (int j = 0; j < 4; ++j)
      bfr[j] = *reinterpret_cast<const bf16x8*>(&Bs[(wn + j * 16 + lrow) * 32 + lk8]);
#pragma unroll
    for (int i = 0; i < 4; ++i)
#pragma unroll
      for (int j = 0; j < 4; ++j)
        acc[i][j] = mfma16(af[i], bfr[j], acc[i][j]);
    __syncthreads();
  }

#pragma unroll
  for (int i = 0; i < 4; ++i) {
#pragma unroll
    for (int j = 0; j < 4; ++j) {
      int col = n0 + wn + j * 16 + lrow;
      float bv = bias[col];
#pragma unroll
      for (int r = 0; r < 4; ++r) {
        int row = m0 + wm + i * 16 + r4 + r;
        float v = acc[i][j][r] + bv;
        if (OUT_BF16) {
          ((unsigned short*)Cv)[(size_t)row * Ndim + col] = f2bfu(v);
        } else {
          ((float*)Cv)[(size_t)row * Ndim + col] = v;
        }
      }
    }
  }
}

// ---------------- Flash attention: swapped QK^T, in-register softmax ----------------
// Block: 256 thr = 4 waves; Q-block 128 rows (wave owns 32); KVBLK 64.
// 32x32x16 MFMA. QK^T computed as mfma(K, Q) -> D[krow][q], q = lane&31.
// C/D layout (m74/m101): col=lane&31, row=(reg&3)+8*(reg>>2)+4*(lane>>5).
// A/B frag: row(col)=lane&31, k=(lane>>5)*8+j.
// Cross-half exchanges use __shfl_xor(.,32) (unambiguous semantics).
__global__ __launch_bounds__(256) void attn_kernel(const unsigned short* __restrict__ mixed,
                                                   const float* __restrict__ mask,
                                                   const unsigned char* __restrict__ flags,
                                                   unsigned short* __restrict__ ctx) {
  __shared__ __align__(16) unsigned short Qs[128 * 64];
  __shared__ __align__(16) unsigned short Ks[2][64 * 64];
  __shared__ __align__(16) unsigned short Vt[2][64 * 64];   // [d][k]

  const int tid = threadIdx.x, wave = tid >> 6, lane = tid & 63;
  const int h = lane >> 5;          // lane half
  const int l31 = lane & 31;
  const int q0 = blockIdx.x * 128;
  const int bh = blockIdx.y;
  const int b = bh / NHH, hh = bh % NHH;

  const unsigned short* qbase = mixed + (size_t)(b * SS) * N1 + hh * 192;
  const unsigned short* kbase = qbase + 64;
  const unsigned short* vbase = qbase + 128;
  const float* mbase = mask + (size_t)b * SS * SS;
  const unsigned char* fl0 = flags + ((size_t)b * 32 + blockIdx.x * 2) * 32;
  const unsigned char* fl1 = fl0 + 32;

  const int vrow = lane;            // V stage: k-row this lane loads
  const int dg = wave;              // V stage: d-group (16 cols) this wave covers

  // ---- prologue: stage Q(128x64), K0, V0 ----
#pragma unroll
  for (int it = 0; it < 4; ++it) {
    int idx = it * 256 + tid;
    int row = idx >> 3, seg = idx & 7;
    load_lds16(qbase + (size_t)(q0 + row) * N1 + ((seg ^ (row & 7)) << 3),
               &Qs[row * 64 + seg * 8]);
  }
#pragma unroll
  for (int it = 0; it < 2; ++it) {
    int idx = it * 256 + tid;
    int row = idx >> 3, seg = idx & 7;
    load_lds16(kbase + (size_t)row * N1 + ((seg ^ (row & 7)) << 3),
               &Ks[0][row * 64 + seg * 8]);
  }
  {
    union { bf16x8 v; unsigned short u[8]; } V0, V1;
    const unsigned short* vp = vbase + (size_t)vrow * N1 + dg * 16;
    V0.v = *reinterpret_cast<const bf16x8*>(vp);
    V1.v = *reinterpret_cast<const bf16x8*>(vp + 8);
#pragma unroll
    for (int j = 0; j < 8; ++j) {
      int d = dg * 16 + j;
      Vt[0][d * 64 + ((((vrow >> 3) ^ (d & 7)) << 3) | (vrow & 7))] = V0.u[j];
    }
#pragma unroll
    for (int j = 0; j < 8; ++j) {
      int d = dg * 16 + 8 + j;
      Vt[0][d * 64 + ((((vrow >> 3) ^ (d & 7)) << 3) | (vrow & 7))] = V1.u[j];
    }
  }
  __syncthreads();

  // ---- hoist Q fragments (B-operand): Q[q=wave*32+l31][d = ds*16 + 8h + j] ----
  bf16x8 qf[4];
#pragma unroll
  for (int ds = 0; ds < 4; ++ds) {
    int row = wave * 32 + l31;
    qf[ds] = *reinterpret_cast<const bf16x8*>(
        &Qs[row * 64 + (((2 * ds + h) ^ (row & 7)) << 3)]);
  }

  f32x16 oacc[2];
#pragma unroll
  for (int i = 0; i < 16; ++i) { oacc[0][i] = 0.f; oacc[1][i] = 0.f; }
  float mrun = -1e30f, lrun = 0.f;

  for (int kt = 0; kt < NT; ++kt) {
    const int cur = kt & 1, nxt = cur ^ 1;
    const int krow0 = kt * 64;
    const bool havenext = (kt + 1 < NT);

    // ---- issue next tile's loads ----
    union { bf16x8 v; unsigned short u[8]; } Vn0, Vn1;
    if (havenext) {
#pragma unroll
      for (int it = 0; it < 2; ++it) {
        int idx = it * 256 + tid;
        int row = idx >> 3, seg = idx & 7;
        load_lds16(kbase + (size_t)(krow0 + 64 + row) * N1 + ((seg ^ (row & 7)) << 3),
                   &Ks[nxt][row * 64 + seg * 8]);
      }
      const unsigned short* vp = vbase + (size_t)(krow0 + 64 + vrow) * N1 + dg * 16;
      Vn0.v = *reinterpret_cast<const bf16x8*>(vp);
      Vn1.v = *reinterpret_cast<const bf16x8*>(vp + 8);
    }

    // ---- QK^T (swapped): sa0 = K[0..31].Q^T, sa1 = K[32..63].Q^T ----
    f32x16 sa0, sa1;
#pragma unroll
    for (int i = 0; i < 16; ++i) { sa0[i] = 0.f; sa1[i] = 0.f; }
    __builtin_amdgcn_s_setprio(1);
#pragma unroll
    for (int ds = 0; ds < 4; ++ds) {
      int r0 = l31, r1 = 32 + l31;
      bf16x8 k0 = *reinterpret_cast<const bf16x8*>(
          &Ks[cur][r0 * 64 + (((2 * ds + h) ^ (r0 & 7)) << 3)]);
      bf16x8 k1 = *reinterpret_cast<const bf16x8*>(
          &Ks[cur][r1 * 64 + (((2 * ds + h) ^ (r1 & 7)) << 3)]);
      sa0 = mfma32(k0, qf[ds], sa0);
      sa1 = mfma32(k1, qf[ds], sa1);
    }
    __builtin_amdgcn_s_setprio(0);

    // ---- softmax (in-register; lane holds q = q0 + wave*32 + l31) ----
    // lane (l31,h) holds krow = (r&3)+8*(r>>2)+4h (sa0: +0, sa1: +32)
    const bool allones = (fl0[kt] & fl1[kt]) != 0;
    float pv0[16], pv1[16];
    float pm = -1e30f;
    if (allones) {
      const float C2 = 0.125f * LOG2E;
#pragma unroll
      for (int r = 0; r < 16; ++r) {
        pv0[r] = sa0[r] * C2; pm = fmaxf(pm, pv0[r]);
        pv1[r] = sa1[r] * C2; pm = fmaxf(pm, pv1[r]);
      }
    } else {
      int qq = q0 + wave * 32 + l31;
#pragma unroll
      for (int r = 0; r < 16; ++r) {
        int krow = (r & 3) + 8 * (r >> 2) + 4 * h;
        {
          int kk = krow0 + krow;
          float mv = mbase[(size_t)qq * SS + kk];
          float s = sa0[r] * 0.125f;
          pv0[r] = (s * mv - 10000.f * (1.f - mv)) * LOG2E;
          pm = fmaxf(pm, pv0[r]);
        }
        {
          int kk = krow0 + 32 + krow;
          float mv = mbase[(size_t)qq * SS + kk];
          float s = sa1[r] * 0.125f;
          pv1[r] = (s * mv - 10000.f * (1.f - mv)) * LOG2E;
          pm = fmaxf(pm, pv1[r]);
        }
      }
    }
    float pmf = fmaxf(pm, __shfl_xor(pm, 32, 64));   // pair max -> row max

    // defer-max (T13): rescale only when the running max actually grows
    if (!__all(pmf <= mrun + 8.f)) {
      float mnew = fmaxf(mrun, pmf);
      float alpha = exp2f(mrun - mnew);   // valid at lane pair for q=l31
      mrun = mnew;
      lrun *= alpha;
#pragma unroll
      for (int r = 0; r < 16; ++r) {
        int qr = (r & 3) + 8 * (r >> 2) + 4 * h;
        float fac = __shfl(alpha, qr, 64);   // lane qr holds alpha for q=qr
        oacc[0][r] *= fac;
        oacc[1][r] *= fac;
      }
    }

    float sum = 0.f;
#pragma unroll
    for (int r = 0; r < 16; ++r) {
      pv0[r] = exp2f(pv0[r] - mrun); sum += pv0[r];
      pv1[r] = exp2f(pv1[r] - mrun); sum += pv1[r];
    }
    lrun += sum + __shfl_xor(sum, 32, 64);

    // ---- pack P to bf16 + cross-half exchange into PV A-fragments ----
    // Lo[kb][m] = k-pair (8m+4h+0, 8m+4h+1); Hi[kb][m] = (8m+4h+2, 8m+4h+3)
    unsigned int Lo[2][4], Hi[2][4];
#pragma unroll
    for (int m = 0; m < 4; ++m) {
      Lo[0][m] = packbf(pv0[4 * m + 0], pv0[4 * m + 1]);
      Hi[0][m] = packbf(pv0[4 * m + 2], pv0[4 * m + 3]);
      Lo[1][m] = packbf(pv1[4 * m + 0], pv1[4 * m + 1]);
      Hi[1][m] = packbf(pv1[4 * m + 2], pv1[4 * m + 3]);
    }
    // A-frag for step ks (k = ks*16 + 8h + j):
    //   w[0]=(k0,k1) w[1]=(k2,k3) w[2]=(k4,k5) w[3]=(k6,k7) relative to 8h base.
    //   h=0 needs own m=2s (w0/w1) + partner(h=1) m=2s (w2/w3);
    //   h=1 needs partner(h=0) m=2s+1 (w0/w1) + own m=2s+1 (w2/w3).
    bf16x8 pa[4];
#pragma unroll
    for (int ks = 0; ks < 4; ++ks) {
      int kb = ks >> 1, s = ks & 1;
      unsigned int sendL = h ? Lo[kb][2 * s] : Lo[kb][2 * s + 1];
      unsigned int recvL = __shfl_xor(sendL, 32, 64);
      unsigned int w0 = h ? recvL : Lo[kb][2 * s];
      unsigned int w2 = h ? Lo[kb][2 * s + 1] : recvL;
      unsigned int sendH = h ? Hi[kb][2 * s] : Hi[kb][2 * s + 1];
      unsigned int recvH = __shfl_xor(sendH, 32, 64);
      unsigned int w1 = h ? recvH : Hi[kb][2 * s];
      unsigned int w3 = h ? Hi[kb][2 * s + 1] : recvH;
      union { bf16x8 v; unsigned int w[4]; } U;
      U.w[0] = w0; U.w[1] = w1; U.w[2] = w2; U.w[3] = w3;
      pa[ks] = U.v;
    }

    // ---- PV: oacc[db] += P . V[:, db*32..+31] ----
    __builtin_amdgcn_s_setprio(1);
#pragma unroll
    for (int ks = 0; ks < 4; ++ks) {
#pragma unroll
      for (int db = 0; db < 2; ++db) {
        int d = db * 32 + l31;
        bf16x8 bv = *reinterpret_cast<const bf16x8*>(
            &Vt[cur][d * 64 + (((2 * ks + h) ^ (d & 7)) << 3)]);
        oacc[db] = mfma32(pa[ks], bv, oacc[db]);
      }
    }
    __builtin_amdgcn_s_setprio(0);

    // ---- write next V tile, then single barrier ----
    if (havenext) {
#pragma unroll
      for (int j = 0; j < 8; ++j) {
        int d = dg * 16 + j;
        Vt[nxt][d * 64 + ((((vrow >> 3) ^ (d & 7)) << 3) | (vrow & 7))] = Vn0.u[j];
      }
#pragma unroll
      for (int j = 0; j < 8; ++j) {
        int d = dg * 16 + 8 + j;
        Vt[nxt][d * 64 + ((((vrow >> 3) ^ (d & 7)) << 3) | (vrow & 7))] = Vn1.u[j];
      }
    }
    __syncthreads();
  }

  // ---- epilogue: gather 1/l per output row via shfl, store ----
  float invl = 1.f / lrun;   // valid at lane pair for q=l31
#pragma unroll
  for (int r = 0; r < 16; ++r) {
    int qr = (r & 3) + 8 * (r >> 2) + 4 * h;
    float inv = __shfl(invl, qr, 64);
    int qq = q0 + wave * 32 + qr;
    unsigned short* cp = ctx + (size_t)(b * SS + qq) * HH + hh * HDD;
    cp[l31] = f2bfu(oacc[0][r] * inv);
    cp[32 + l31] = f2bfu(oacc[1][r] * inv);
  }
}

extern "C" void kernel_launch(void* const* d_in, const int* in_sizes, int n_in,
                              void* d_out, int out_size, void* d_ws, size_t ws_size,
                              hipStream_t stream) {
  const float* hs      = (const float*)d_in[0];
  const float* mask    = (const float*)d_in[1];
  const float* qkv_w   = (const float*)d_in[2];
  const float* qkv_b   = (const float*)d_in[3];
  const float* dense_w = (const float*)d_in[4];
  const float* dense_b = (const float*)d_in[5];
  float* out = (float*)d_out;

  char* ws = (char*)d_ws;
  unsigned short* hs_b     = (unsigned short*)(ws);                 // 4096x1024
  unsigned short* qkvw_b   = (unsigned short*)(ws + 8388608);       // 3072x1024
  unsigned short* densew_b = (unsigned short*)(ws + 14680064);      // 1024x1024
  unsigned short* mixed_b  = (unsigned short*)(ws + 16777216);      // 4096x3072
  unsigned short* ctx_b    = (unsigned short*)(ws + 41943040);      // 4096x1024
  unsigned char*  flags    = (unsigned char*)(ws + 50331648);       // 2048 bytes

  cvt_f32_bf16<<<2048, 256, 0, stream>>>(hs, hs_b, (MM * HH) / 4);
  cvt_f32_bf16<<<2048, 256, 0, stream>>>(qkv_w, qkvw_b, (N1 * HH) / 4);
  cvt_f32_bf16<<<1024, 256, 0, stream>>>(dense_w, densew_b, (HH * HH) / 4);
  mask_flags_kernel<<<BB * 32 * 32, 256, 0, stream>>>(mask, flags);

  gemm_bt<true><<<dim3(MM / 128, N1 / 128), 256, 0, stream>>>(
      hs_b, qkvw_b, qkv_b, mixed_b, N1, HH);

  attn_kernel<<<dim3(SS / 128, BB * NHH), 256, 0, stream>>>(mixed_b, mask, flags, ctx_b);

  gemm_bt<false><<<dim3(MM / 128, HH / 128), 256, 0, stream>>>(
      ctx_b, densew_b, dense_b, out, HH, HH);
}

// Round 5
// 169.556 us; speedup vs baseline: 1.3357x; 1.3357x over previous
//
#include <hip/hip_runtime.h>
#include <hip/hip_bf16.h>
#include <stdint.h>

#define BB 2
#define SS 2048
#define HH 1024
#define NHH 16
#define HDD 64
#define MM (BB*SS)      // 4096
#define N1 (3*HH)       // 3072
#define NT (SS/64)      // 32 kv tiles
#define LOG2E 1.44269504f

using bf16 = __hip_bfloat16;
typedef __attribute__((ext_vector_type(8))) short bf16x8;
typedef __attribute__((ext_vector_type(4))) float f32x4;

__device__ inline unsigned short f2bfu(float f) {
  union { bf16 h; unsigned short u; } c;
  c.h = __float2bfloat16(f);
  return c.u;
}

__device__ inline unsigned int packbf(float lo, float hi) {
  return (unsigned int)f2bfu(lo) | ((unsigned int)f2bfu(hi) << 16);
}

__device__ inline void load_lds16(const void* g, void* l) {
  __builtin_amdgcn_global_load_lds(
      (const __attribute__((address_space(1))) void*)g,
      (__attribute__((address_space(3))) void*)l, 16, 0, 0);
}

__device__ inline f32x4 mfma16(bf16x8 a, bf16x8 b, f32x4 c) {
  return __builtin_amdgcn_mfma_f32_16x16x32_bf16(a, b, c, 0, 0, 0);
}

// ---------------- fp32 -> bf16 convert ----------------
__global__ __launch_bounds__(256) void cvt_f32_bf16(const float* __restrict__ in,
                                                    unsigned short* __restrict__ out,
                                                    int n4) {
  int i = blockIdx.x * blockDim.x + threadIdx.x;
  int st = gridDim.x * blockDim.x;
  for (; i < n4; i += st) {
    float4 v = reinterpret_cast<const float4*>(in)[i];
    ushort4 o;
    o.x = f2bfu(v.x); o.y = f2bfu(v.y); o.z = f2bfu(v.z); o.w = f2bfu(v.w);
    reinterpret_cast<ushort4*>(out)[i] = o;
  }
}

// ---------------- mask tile flags: 1 if 64x64 tile is all ones ----------------
__global__ __launch_bounds__(256) void mask_flags_kernel(const float* __restrict__ mask,
                                                         unsigned char* __restrict__ flags) {
  int t = blockIdx.x;
  int b = t >> 10, qt = (t >> 5) & 31, kt = t & 31;
  const float* mb = mask + ((size_t)b * SS + qt * 64) * SS + kt * 64;
  int row = threadIdx.x >> 2, c0 = (threadIdx.x & 3) * 16;
  int ok = 1;
#pragma unroll
  for (int j = 0; j < 4; ++j) {
    float4 v = *reinterpret_cast<const float4*>(mb + (size_t)row * SS + c0 + j * 4);
    ok &= (v.x == 1.f) & (v.y == 1.f) & (v.z == 1.f) & (v.w == 1.f);
  }
  ok = __all(ok);
  __shared__ int s[4];
  if ((threadIdx.x & 63) == 0) s[threadIdx.x >> 6] = ok;
  __syncthreads();
  if (threadIdx.x == 0) flags[t] = (unsigned char)(s[0] & s[1] & s[2] & s[3]);
}

// ---------------- GEMM: C[m][n] = sum_k A[m][k]*Bt[n][k] + bias[n] ----------------
template <bool OUT_BF16>
__global__ __launch_bounds__(256) void gemm_bt(const unsigned short* __restrict__ A,
                                               const unsigned short* __restrict__ Bt,
                                               const float* __restrict__ bias,
                                               void* __restrict__ Cv,
                                               int Ndim, int Kdim) {
  __shared__ __align__(16) unsigned short As[128 * 32];
  __shared__ __align__(16) unsigned short Bs[128 * 32];

  const int tid = threadIdx.x;
  const int wave = tid >> 6, lane = tid & 63;
  const int m0 = blockIdx.x * 128;
  const int n0 = blockIdx.y * 128;
  const int wm = (wave >> 1) * 64, wn = (wave & 1) * 64;
  const int lrow = lane & 15;
  const int lk8 = (lane >> 4) * 8;
  const int r4 = (lane >> 4) * 4;

  f32x4 acc[4][4];
  const f32x4 z = {0.f, 0.f, 0.f, 0.f};
  for (int i = 0; i < 4; ++i)
    for (int j = 0; j < 4; ++j) acc[i][j] = z;

  for (int k0 = 0; k0 < Kdim; k0 += 32) {
#pragma unroll
    for (int it = 0; it < 2; ++it) {
      int idx = it * 256 + tid;
      int row = idx >> 2, seg = idx & 3;
      load_lds16(A + (size_t)(m0 + row) * Kdim + k0 + seg * 8, &As[row * 32 + seg * 8]);
      load_lds16(Bt + (size_t)(n0 + row) * Kdim + k0 + seg * 8, &Bs[row * 32 + seg * 8]);
    }
    __syncthreads();

    bf16x8 af[4], bfr[4];
#pragma unroll
    for (int i = 0; i < 4; ++i)
      af[i] = *reinterpret_cast<const bf16x8*>(&As[(wm + i * 16 + lrow) * 32 + lk8]);
#pragma unroll
    for (int j = 0; j < 4; ++j)
      bfr[j] = *reinterpret_cast<const bf16x8*>(&Bs[(wn + j * 16 + lrow) * 32 + lk8]);
#pragma unroll
    for (int i = 0; i < 4; ++i)
#pragma unroll
      for (int j = 0; j < 4; ++j)
        acc[i][j] = mfma16(af[i], bfr[j], acc[i][j]);
    __syncthreads();
  }

#pragma unroll
  for (int i = 0; i < 4; ++i) {
#pragma unroll
    for (int j = 0; j < 4; ++j) {
      int col = n0 + wn + j * 16 + lrow;
      float bv = bias[col];
#pragma unroll
      for (int r = 0; r < 4; ++r) {
        int row = m0 + wm + i * 16 + r4 + r;
        float v = acc[i][j][r] + bv;
        if (OUT_BF16) {
          ((unsigned short*)Cv)[(size_t)row * Ndim + col] = f2bfu(v);
        } else {
          ((float*)Cv)[(size_t)row * Ndim + col] = v;
        }
      }
    }
  }
}

// ---------------- Flash attention: swapped QK^T, in-register softmax, 16-row waves --
// Block 256 = 4 waves; Q-tile 64 (wave owns 16 q-rows); KVBLK 64. Grid (32, B*NH).
// QK^T as mfma16(Kfrag, Qfrag) -> D[krow][q]: q = lane&15, krow = 16n + 4g + r
// (g = lane>>4). Softmax per lane over 16 scores; 2 shfl_xor for row reduce.
// P staged via 4 ds_write_b64 to wave-private LDS (aliases Q tile), read back as
// 2 ds_read_b128 A-fragments. V transposed to [d][k] at stage time (as R2, 0-conflict).
// All LDS XOR-swizzled; global_load_lds sources pre-swizzled (rule #21).
__global__ __launch_bounds__(256, 4) void attn_kernel(const unsigned short* __restrict__ mixed,
                                                      const float* __restrict__ mask,
                                                      const unsigned char* __restrict__ flags,
                                                      unsigned short* __restrict__ ctx) {
  __shared__ __align__(16) unsigned short Ks[2][64 * 64];
  __shared__ __align__(16) unsigned short Vt[2][64 * 64];   // [d][k]
  __shared__ __align__(16) unsigned short QP[64 * 64];      // Q tile, then P (per-wave)

  const int tid = threadIdx.x, wave = tid >> 6, lane = tid & 63;
  const int ql = lane & 15;         // q within wave-tile (QK^T) / d within block (PV)
  const int g = lane >> 4;          // 4-lane-group
  const int q0 = blockIdx.x * 64;
  const int bh = blockIdx.y;
  const int b = bh / NHH, hh = bh % NHH;

  const unsigned short* qbase = mixed + (size_t)(b * SS) * N1 + hh * 192;
  const unsigned short* kbase = qbase + 64;
  const unsigned short* vbase = qbase + 128;
  const float* mbase = mask + (size_t)b * SS * SS;
  const unsigned char* fl = flags + ((size_t)b * 32 + blockIdx.x) * 32;

  const int vrow = lane;            // V stage: k-row this lane loads
  const int dg = wave;              // V stage: d-group (16 cols) this wave covers

  // ---- prologue: stage Q, K0, V0 ----
#pragma unroll
  for (int it = 0; it < 2; ++it) {
    int idx = it * 256 + tid;
    int row = idx >> 3, seg = idx & 7;
    load_lds16(qbase + (size_t)(q0 + row) * N1 + ((seg ^ (row & 7)) << 3),
               &QP[row * 64 + seg * 8]);
    load_lds16(kbase + (size_t)row * N1 + ((seg ^ (row & 7)) << 3),
               &Ks[0][row * 64 + seg * 8]);
  }
  {
    union { bf16x8 v; unsigned short u[8]; } V0, V1;
    const unsigned short* vp = vbase + (size_t)vrow * N1 + dg * 16;
    V0.v = *reinterpret_cast<const bf16x8*>(vp);
    V1.v = *reinterpret_cast<const bf16x8*>(vp + 8);
#pragma unroll
    for (int j = 0; j < 8; ++j) {
      int d = dg * 16 + j;
      Vt[0][d * 64 + ((((vrow >> 3) ^ (d & 7)) << 3) | (vrow & 7))] = V0.u[j];
    }
#pragma unroll
    for (int j = 0; j < 8; ++j) {
      int d = dg * 16 + 8 + j;
      Vt[0][d * 64 + ((((vrow >> 3) ^ (d & 7)) << 3) | (vrow & 7))] = V1.u[j];
    }
  }
  __syncthreads();

  // ---- hoist Q fragments (B-operand: col=q=ql, k-elems d = g*8+j / 32+g*8+j) ----
  const int qrow = wave * 16 + ql;
  const bf16x8 qf0 = *reinterpret_cast<const bf16x8*>(
      &QP[qrow * 64 + ((g ^ (qrow & 7)) << 3)]);
  const bf16x8 qf1 = *reinterpret_cast<const bf16x8*>(
      &QP[qrow * 64 + (((g + 4) ^ (qrow & 7)) << 3)]);
  __syncthreads();   // everyone done reading Q before P overwrites it

  unsigned short* Ps = &QP[wave * 1024];   // wave-private 16 x 64
  const int X = (ql & 7) << 3;             // P swizzle (elem units)

  f32x4 oacc[4];
  const f32x4 z = {0.f, 0.f, 0.f, 0.f};
  for (int fd = 0; fd < 4; ++fd) oacc[fd] = z;
  float mrun = -1e30f, lrun = 0.f;

  for (int kt = 0; kt < NT; ++kt) {
    const int cur = kt & 1, nxt = cur ^ 1;
    const int krow0 = kt * 64;
    const bool havenext = (kt + 1 < NT);

    // ---- issue next tile's loads (overlap with compute) ----
    union { bf16x8 v; unsigned short u[8]; } Vn0, Vn1;
    if (havenext) {
#pragma unroll
      for (int it = 0; it < 2; ++it) {
        int idx = it * 256 + tid;
        int row = idx >> 3, seg = idx & 7;
        load_lds16(kbase + (size_t)(krow0 + 64 + row) * N1 + ((seg ^ (row & 7)) << 3),
                   &Ks[nxt][row * 64 + seg * 8]);
      }
      const unsigned short* vp = vbase + (size_t)(krow0 + 64 + vrow) * N1 + dg * 16;
      Vn0.v = *reinterpret_cast<const bf16x8*>(vp);
      Vn1.v = *reinterpret_cast<const bf16x8*>(vp + 8);
    }

    // ---- QK^T swapped: sacc[n] = D[krow = 16n+4g+r][q = ql] ----
    f32x4 sacc[4];
    __builtin_amdgcn_s_setprio(1);
#pragma unroll
    for (int n = 0; n < 4; ++n) {
      int krow = n * 16 + ql;
      bf16x8 k0 = *reinterpret_cast<const bf16x8*>(
          &Ks[cur][krow * 64 + ((g ^ (krow & 7)) << 3)]);
      bf16x8 k1 = *reinterpret_cast<const bf16x8*>(
          &Ks[cur][krow * 64 + (((g + 4) ^ (krow & 7)) << 3)]);
      sacc[n] = mfma16(k0, qf0, z);
      sacc[n] = mfma16(k1, qf1, sacc[n]);
    }
    __builtin_amdgcn_s_setprio(0);

    // ---- softmax (lane holds q = q0 + wave*16 + ql; k = krow0 + 16n + 4g + r) ----
    const bool allones = fl[kt] != 0;
    float pv[4][4];
    float pm = -1e30f;
    if (allones) {
      const float C2 = 0.125f * LOG2E;
#pragma unroll
      for (int n = 0; n < 4; ++n)
#pragma unroll
        for (int r = 0; r < 4; ++r) {
          pv[n][r] = sacc[n][r] * C2;
          pm = fmaxf(pm, pv[n][r]);
        }
    } else {
      int qq = q0 + wave * 16 + ql;
#pragma unroll
      for (int n = 0; n < 4; ++n)
#pragma unroll
        for (int r = 0; r < 4; ++r) {
          int kk = krow0 + 16 * n + 4 * g + r;
          float mv = mbase[(size_t)qq * SS + kk];
          float s = sacc[n][r] * 0.125f;
          pv[n][r] = (s * mv - 10000.f * (1.f - mv)) * LOG2E;
          pm = fmaxf(pm, pv[n][r]);
        }
    }
    float pmf = fmaxf(pm, __shfl_xor(pm, 16, 64));
    pmf = fmaxf(pmf, __shfl_xor(pmf, 32, 64));   // row max, replicated over groups

    // defer-max (T13): rescale only when the running max grows past threshold
    if (!__all(pmf <= mrun + 8.f)) {
      float mnew = fmaxf(mrun, pmf);
      float alpha = exp2f(mrun - mnew);   // valid for q = ql at this lane
      mrun = mnew;
      lrun *= alpha;
#pragma unroll
      for (int r = 0; r < 4; ++r) {
        float fac = __shfl(alpha, g * 4 + r, 64);   // lane g*4+r holds q=g*4+r
#pragma unroll
        for (int fd = 0; fd < 4; ++fd) oacc[fd][r] *= fac;
      }
    }

    float sum = 0.f;
#pragma unroll
    for (int n = 0; n < 4; ++n)
#pragma unroll
      for (int r = 0; r < 4; ++r) {
        pv[n][r] = exp2f(pv[n][r] - mrun);
        sum += pv[n][r];
      }
    sum += __shfl_xor(sum, 16, 64);
    sum += __shfl_xor(sum, 32, 64);
    lrun += sum;

    // ---- P -> wave-private LDS: row q=ql, elems k ^ X (4 x ds_write_b64) ----
#pragma unroll
    for (int n = 0; n < 4; ++n) {
      uint2 w;
      w.x = packbf(pv[n][0], pv[n][1]);
      w.y = packbf(pv[n][2], pv[n][3]);
      *reinterpret_cast<uint2*>(&Ps[ql * 64 + ((16 * n + 4 * g) ^ X)]) = w;
    }
    // A-fragments: row q=ql, k = g*8..+7 (kb=0) and 32+g*8..+7 (kb=1)
    bf16x8 pa0 = *reinterpret_cast<const bf16x8*>(&Ps[ql * 64 + ((8 * g) ^ X)]);
    bf16x8 pa1 = *reinterpret_cast<const bf16x8*>(&Ps[ql * 64 + ((32 + 8 * g) ^ X)]);

    // ---- PV: oacc[fd] += P . V[:, fd*16 + ql] ----
    __builtin_amdgcn_s_setprio(1);
#pragma unroll
    for (int fd = 0; fd < 4; ++fd) {
      int d = fd * 16 + ql;
      bf16x8 bv0 = *reinterpret_cast<const bf16x8*>(
          &Vt[cur][d * 64 + ((g ^ (d & 7)) << 3)]);
      bf16x8 bv1 = *reinterpret_cast<const bf16x8*>(
          &Vt[cur][d * 64 + (((4 + g) ^ (d & 7)) << 3)]);
      oacc[fd] = mfma16(pa0, bv0, oacc[fd]);
      oacc[fd] = mfma16(pa1, bv1, oacc[fd]);
    }
    __builtin_amdgcn_s_setprio(0);

    // ---- write next V tile (reg->LDS), then single barrier ----
    if (havenext) {
#pragma unroll
      for (int j = 0; j < 8; ++j) {
        int d = dg * 16 + j;
        Vt[nxt][d * 64 + ((((vrow >> 3) ^ (d & 7)) << 3) | (vrow & 7))] = Vn0.u[j];
      }
#pragma unroll
      for (int j = 0; j < 8; ++j) {
        int d = dg * 16 + 8 + j;
        Vt[nxt][d * 64 + ((((vrow >> 3) ^ (d & 7)) << 3) | (vrow & 7))] = Vn1.u[j];
      }
    }
    __syncthreads();
  }

  // ---- epilogue: O row q = g*4+r, col d = fd*16+ql ----
  float invl = 1.f / lrun;   // valid for q = ql at this lane
#pragma unroll
  for (int r = 0; r < 4; ++r) {
    float inv = __shfl(invl, g * 4 + r, 64);
    int qq = q0 + wave * 16 + g * 4 + r;
    unsigned short* cp = ctx + (size_t)(b * SS + qq) * HH + hh * HDD;
#pragma unroll
    for (int fd = 0; fd < 4; ++fd)
      cp[fd * 16 + ql] = f2bfu(oacc[fd][r] * inv);
  }
}

extern "C" void kernel_launch(void* const* d_in, const int* in_sizes, int n_in,
                              void* d_out, int out_size, void* d_ws, size_t ws_size,
                              hipStream_t stream) {
  const float* hs      = (const float*)d_in[0];
  const float* mask    = (const float*)d_in[1];
  const float* qkv_w   = (const float*)d_in[2];
  const float* qkv_b   = (const float*)d_in[3];
  const float* dense_w = (const float*)d_in[4];
  const float* dense_b = (const float*)d_in[5];
  float* out = (float*)d_out;

  char* ws = (char*)d_ws;
  unsigned short* hs_b     = (unsigned short*)(ws);                 // 4096x1024
  unsigned short* qkvw_b   = (unsigned short*)(ws + 8388608);       // 3072x1024
  unsigned short* densew_b = (unsigned short*)(ws + 14680064);      // 1024x1024
  unsigned short* mixed_b  = (unsigned short*)(ws + 16777216);      // 4096x3072
  unsigned short* ctx_b    = (unsigned short*)(ws + 41943040);      // 4096x1024
  unsigned char*  flags    = (unsigned char*)(ws + 50331648);       // 2048 bytes

  cvt_f32_bf16<<<2048, 256, 0, stream>>>(hs, hs_b, (MM * HH) / 4);
  cvt_f32_bf16<<<2048, 256, 0, stream>>>(qkv_w, qkvw_b, (N1 * HH) / 4);
  cvt_f32_bf16<<<1024, 256, 0, stream>>>(dense_w, densew_b, (HH * HH) / 4);
  mask_flags_kernel<<<BB * 32 * 32, 256, 0, stream>>>(mask, flags);

  gemm_bt<true><<<dim3(MM / 128, N1 / 128), 256, 0, stream>>>(
      hs_b, qkvw_b, qkv_b, mixed_b, N1, HH);

  attn_kernel<<<dim3(SS / 64, BB * NHH), 256, 0, stream>>>(mixed_b, mask, flags, ctx_b);

  gemm_bt<false><<<dim3(MM / 128, HH / 128), 256, 0, stream>>>(
      ctx_b, densew_b, dense_b, out, HH, HH);
}